// Round 1
// baseline (145.538 us; speedup 1.0000x reference)
//
#include <hip/hip_runtime.h>
#include <hip/hip_cooperative_groups.h>

namespace cg = cooperative_groups;

#define RNODES 1152
#define KDIM 9216                 // 1152*8
#define COUT 16
#define NCAPS 10
#define WSTRIDE (KDIM*COUT)       // 147456 floats per capsule

#define LROW 40                   // 32 k + 8 pad (ushorts) -> 80B rows, 16B-aligned reads
#define WBUF (NCAPS*COUT*LROW)    // 6400 ushorts = 12.8 KB per buffer
#define STEPS 9                   // k-steps of 32 per block
#define SPLITS 32                 // 32 * 9 * 32 = 9216 = KDIM
#define NBLK 256                  // 8 M-tiles x 32 splits = 1 block/CU exactly
#define PARTL (32*COUT*NCAPS)     // 5120 floats per block partial (32 rows)
#define PARTL4 (PARTL/4)          // 1280 float4

using bf16x8 = __attribute__((ext_vector_type(8))) short;
using f32x4  = __attribute__((ext_vector_type(4))) float;

// round-to-nearest (ties up): 2 VALU ops; unbiased to 2^-9 rel — same as R6.
__device__ __forceinline__ unsigned short f2bf(float f) {
  unsigned int u = __builtin_bit_cast(unsigned int, f);
  return (unsigned short)((u + 0x8000u) >> 16);
}

// R9: single cooperative kernel = R8 caps_gemm (phase 1, UNCHANGED) + grid.sync()
// + fused reduce/squash (phase 2). Removes the second launch and reads the 5.2 MB
// partials while they are still L2/L3-resident instead of a cold HBM round-trip.
//
// Phase 1 notes (identical to R8):
//  * grid = 256 (one block/CU). bid = mt*32 + ks -> XCD = ks%8: all 8 mt-blocks
//    sharing W-slice ks sit on ONE XCD -> W re-reads are L2 hits.
//  * W staging decode is slab-contiguous: unit u = j*256+tid -> n=u>>7,
//    kl=(u&127)>>2, o4=(u&3)*4 -> every W load is a 1KB fully-coalesced wave txn.
//  * LDS layout: col c stores k-block t at ((t + (c&3) + ((c>>2)&3)) & 3);
//    writes 2-way bank aliasing (free, m136); reads b128 16B-aligned contiguous.
__global__ __launch_bounds__(256, 1) void caps_fused(const float* __restrict__ x,
                                                     const float* __restrict__ W,
                                                     float* __restrict__ ws,
                                                     float* __restrict__ out) {
  __shared__ unsigned short wbuf[2][WBUF];   // ping-pong, 25.6 KB
  const int tid = threadIdx.x;
  const int bid = blockIdx.x;
  const int mt  = bid >> 5;         // 0..7  (32-row M-tile)
  const int ks  = bid & 31;         // 0..31 (K split)
  const int b0  = mt * 32;
  const int k0  = ks * (STEPS * 32);   // 288-element K chunk

  const int lane = tid & 63;
  const int wv   = tid >> 6;
  const int p    = wv >> 1;         // row half
  const int h    = wv & 1;          // capsule half
  const int q    = lane >> 4;       // k-quad
  const int m16  = lane & 15;

  // ---- slab-contiguous staging decode (5 units/thread covers 1280 float4) ----
  int u_n[5], u_kl[5], u_of[5];
#pragma unroll
  for (int j = 0; j < 5; ++j) {
    const int u  = j * 256 + tid;
    u_n[j]  = u >> 7;               // capsule slab 0..9
    const int rem = u & 127;
    u_kl[j] = rem >> 2;             // k within step, 0..31
    u_of[j] = (rem & 3) << 2;       // o-quad base 0,4,8,12
  }

  const float* xrow = x + (size_t)(b0 + p * 16 + m16) * KDIM + k0 + q * 8;

  float4 pw[3][5];
  float4 pa[3][2];

  auto load_step = [&](int s, int slot) {
#pragma unroll
    for (int j = 0; j < 5; ++j)
      pw[slot][j] = *(const float4*)(W + (size_t)u_n[j] * WSTRIDE +
                                     (size_t)(k0 + s * 32 + u_kl[j]) * COUT + u_of[j]);
    pa[slot][0] = *(const float4*)(xrow + s * 32);
    pa[slot][1] = *(const float4*)(xrow + s * 32 + 4);
  };

  load_step(0, 0);
  load_step(1, 1);
  load_step(2, 2);

  f32x4 acc[5];
#pragma unroll
  for (int i = 0; i < 5; ++i) acc[i] = (f32x4){0.f, 0.f, 0.f, 0.f};

  // per-lane rotated read quad (k-block) — same for every capsule
  const int qrot = (q + (m16 & 3) + (m16 >> 2)) & 3;

#pragma unroll
  for (int s = 0; s < STEPS; ++s) {
    const int slot = s % 3;
    unsigned short* b = &wbuf[s & 1][0];
    // stage W step s: [col][k-rotated] bf16 transpose
#pragma unroll
    for (int j = 0; j < 5; ++j) {
      const int kl  = u_kl[j];
      const int klo = kl & 7, kblk = kl >> 3;
      const float* v = (const float*)&pw[slot][j];
#pragma unroll
      for (int r = 0; r < 4; ++r) {
        const int c   = u_n[j] * COUT + u_of[j] + r;
        const int pos = klo | (((kblk + (c & 3) + ((c >> 2) & 3)) & 3) << 3);
        b[c * LROW + pos] = f2bf(v[r]);
      }
    }
    __syncthreads();
    // write(s+2) to this parity happens after barrier(s+1); reads(s) drain
    // before barrier(s+1) -> classic 2-buffer safety, 1 barrier/step.

    bf16x8 a;
    a[0] = (short)f2bf(pa[slot][0].x); a[1] = (short)f2bf(pa[slot][0].y);
    a[2] = (short)f2bf(pa[slot][0].z); a[3] = (short)f2bf(pa[slot][0].w);
    a[4] = (short)f2bf(pa[slot][1].x); a[5] = (short)f2bf(pa[slot][1].y);
    a[6] = (short)f2bf(pa[slot][1].z); a[7] = (short)f2bf(pa[slot][1].w);

    if (s + 3 < STEPS) load_step(s + 3, slot);   // slot just freed

#pragma unroll
    for (int j = 0; j < 5; ++j) {
      const int nt = h * 5 + j;
      bf16x8 bf = *(const bf16x8*)&b[(nt * COUT + m16) * LROW + (qrot << 3)];
      acc[j] = __builtin_amdgcn_mfma_f32_16x16x32_bf16(a, bf, acc[j], 0, 0, 0);
    }
  }

  // ---- partial store: P[bid][n][row32][o] ----
  float* P = ws + (size_t)bid * PARTL;
  const int prow = p * 16 + q * 4;   // C/D: col=lane&15 (=o), row=q*4+reg
#pragma unroll
  for (int j = 0; j < 5; ++j)
#pragma unroll
    for (int r = 0; r < 4; ++r)
      P[(h * 5 + j) * 512 + (prow + r) * COUT + m16] = acc[j][r];

  // ---- grid-wide sync: partials visible device-wide (release/acquire incl.
  // cross-XCD L2 handling is inside cg's grid barrier) ----
  __threadfence();
  cg::this_grid().sync();

  // ---- phase 2: reduce + squash. One thread per output float.
  // f = n*4096 + b*16 + o; 16 consecutive lanes = one (n,b) o-vector.
  // Per kk, a wave reads 64 consecutive floats (256 B, coalesced); the 32
  // split-partials are hot in L2/L3 behind the sync. Sum order (s0..s3,
  // stride-4 interleave, pairwise combine) is IDENTICAL to the R8 reducer
  // -> bitwise-identical output.
  const int f = bid * 256 + tid;     // 0..65535; active < 40960
  if (f < NCAPS * 256 * COUT) {
    const int n   = f >> 12;         // capsule
    const int bb  = (f >> 4) & 255;  // batch row
    const int o   = f & 15;
    const int fmt = bb >> 5, row = bb & 31;

    const float* base = ws + (size_t)(fmt * SPLITS) * PARTL + n * 512 + row * COUT + o;
    float s0 = 0.f, s1 = 0.f, s2 = 0.f, s3 = 0.f;
#pragma unroll
    for (int kk = 0; kk < SPLITS; kk += 4) {
      s0 += base[(size_t)(kk + 0) * PARTL];
      s1 += base[(size_t)(kk + 1) * PARTL];
      s2 += base[(size_t)(kk + 2) * PARTL];
      s3 += base[(size_t)(kk + 3) * PARTL];
    }
    const float inv = 1.0f / (float)RNODES;
    float s = ((s0 + s1) + (s2 + s3)) * inv;

    float sq = s * s;                // reduce over the 16-lane o-group
    sq += __shfl_xor(sq, 1);
    sq += __shfl_xor(sq, 2);
    sq += __shfl_xor(sq, 4);
    sq += __shfl_xor(sq, 8);
    const float g = sqrtf(sq) / (1.0f + sq);
    out[f] = s * g;
  }
}

extern "C" void kernel_launch(void* const* d_in, const int* in_sizes, int n_in,
                              void* d_out, int out_size, void* d_ws, size_t ws_size,
                              hipStream_t stream) {
  const float* x = (const float*)d_in[0];   // [256,1152,8] fp32
  const float* W = (const float*)d_in[1];   // [10,1152,8,16] fp32
  float* ws  = (float*)d_ws;                // 256*5120 fp32 partials (5.2 MB)
  float* out = (float*)d_out;               // 40960 fp32

  void* args[] = {(void*)&x, (void*)&W, (void*)&ws, (void*)&out};
  hipLaunchCooperativeKernel((const void*)caps_fused, dim3(NBLK), dim3(256),
                             args, 0, stream);
}

// Round 2
// 82.055 us; speedup vs baseline: 1.7737x; 1.7737x over previous
//
#include <hip/hip_runtime.h>

#define RNODES 1152
#define KDIM 9216                 // 1152*8
#define COUT 16
#define NCAPS 10
#define WSTRIDE (KDIM*COUT)       // 147456 floats per capsule

#define LROW 40                   // 32 k + 8 pad (ushorts) -> 80B rows, 16B-aligned b128 reads
#define WVSTEPS 36                // k-steps of 32 per wave: 36*32 = 1152 = KDIM/8
#define MT 16                     // rows per block
#define NBLK 160                  // bid = n*16 + mt -> bid%8 == mt%8: all 10 capsule-blocks
                                  // of an m-tile share one XCD -> x re-reads are L2 hits

using bf16x8 = __attribute__((ext_vector_type(8))) short;
using f32x4  = __attribute__((ext_vector_type(4))) float;

// round-to-nearest (ties up): 2 VALU ops; unbiased to 2^-9 rel — same as R8.
__device__ __forceinline__ unsigned short f2bf(float f) {
  unsigned int u = __builtin_bit_cast(unsigned int, f);
  return (unsigned short)((u + 0x8000u) >> 16);
}

// R10: single regular kernel, NO split-K workspace, NO __syncthreads in the main
// loop, NO second dispatch.
//  * 160 blocks x 512 threads: block = (capsule n, 16-row m-tile). 8 waves split
//    K=9216 into private 1152-chunks (36 steps of 32) -> 2 waves/SIMD TLP.
//  * Each wave stages ITS OWN W k-chunk into a wave-private LDS tile (double-
//    buffered). Same-wave ds_write -> ds_read needs only lgkmcnt (compiler-
//    inserted), so the 36-step loop has ZERO block barriers (R8 had 9).
//  * LDS layout per 16-col tile is byte-identical to R8's proven transpose:
//    col c stores k-block t at ((t + (c&3) + ((c>>2)&3)) & 3); reads are
//    16B-aligned ds_read_b128 at qrot = (q + (m16&3) + (m16>>2)) & 3 —
//    conflict-free (R8-verified pattern).
//  * W global loads: unit u = e*64+lane -> float4 u of the 32k x 16o chunk ->
//    two fully-coalesced 1KB wave transactions per step.
//  * 3-deep register prefetch (pw/pa slots) covers ~600+ cyc of HBM latency.
//  * Tail: fixed-order pairwise LDS reduce over the 8 wave-accs (deterministic),
//    squash over 16-lane o-groups, coalesced store straight to out.
__global__ __launch_bounds__(512, 2) void caps_one(const float* __restrict__ x,
                                                   const float* __restrict__ W,
                                                   float* __restrict__ out) {
  __shared__ __align__(16) unsigned short wtile[8][2][16 * LROW]; // 20.5 KB
  __shared__ float redbuf[8][256];                                // 8 KB

  const int tid  = threadIdx.x;
  const int bid  = blockIdx.x;
  const int n    = bid >> 4;        // capsule 0..9
  const int mt   = bid & 15;        // m-tile 0..15
  const int b0   = mt * MT;

  const int wv   = tid >> 6;        // 0..7: wave = private K-chunk
  const int lane = tid & 63;
  const int q    = lane >> 4;       // k-quad
  const int m16  = lane & 15;       // A: row / B: col / C: col

  const float* wbase = W + (size_t)n * WSTRIDE + (size_t)wv * 1152 * COUT;
  const float* xrow  = x + (size_t)(b0 + m16) * KDIM + wv * 1152 + q * 8;

  float4 pw[3][2];                  // 3-deep W prefetch (2 float4/step)
  float4 pa[3][2];                  // 3-deep x prefetch

  auto load_step = [&](int s, int slot) {
#pragma unroll
    for (int e = 0; e < 2; ++e)     // float4 u = e*64+lane: k=u>>2, o4=(u&3)*4
      pw[slot][e] = *(const float4*)(wbase + (size_t)s * 32 * COUT + (e * 64 + lane) * 4);
    pa[slot][0] = *(const float4*)(xrow + s * 32);
    pa[slot][1] = *(const float4*)(xrow + s * 32 + 4);
  };

  auto stage = [&](int slot, int buf) {
    unsigned short* bp = &wtile[wv][buf][0];
#pragma unroll
    for (int e = 0; e < 2; ++e) {
      const int k    = e * 16 + (lane >> 2);
      const int klo  = k & 7, kblk = k >> 3;
      const int o4   = (lane & 3) << 2;
      const float* v = (const float*)&pw[slot][e];
#pragma unroll
      for (int r = 0; r < 4; ++r) {
        const int c   = o4 + r;
        const int pos = klo | (((kblk + (c & 3) + ((c >> 2) & 3)) & 3) << 3);
        bp[c * LROW + pos] = f2bf(v[r]);
      }
    }
  };

  load_step(0, 0);
  load_step(1, 1);
  load_step(2, 2);
  stage(0, 0);

  f32x4 acc = (f32x4){0.f, 0.f, 0.f, 0.f};
  const int qrot = (q + (m16 & 3) + (m16 >> 2)) & 3;
  const unsigned short* rd0 = &wtile[wv][0][m16 * LROW + (qrot << 3)];
  const unsigned short* rd1 = &wtile[wv][1][m16 * LROW + (qrot << 3)];

  // per step s: consume pa[s%3] -> a; read b-frag from buf s&1; refill slot s%3
  // with step s+3 (3-step HBM cover); MFMA; stage step s+1 into the other buf.
  auto body = [&](int s, int slotA, int bufR, int slotN, int bufN) {
    bf16x8 a;
    a[0] = (short)f2bf(pa[slotA][0].x); a[1] = (short)f2bf(pa[slotA][0].y);
    a[2] = (short)f2bf(pa[slotA][0].z); a[3] = (short)f2bf(pa[slotA][0].w);
    a[4] = (short)f2bf(pa[slotA][1].x); a[5] = (short)f2bf(pa[slotA][1].y);
    a[6] = (short)f2bf(pa[slotA][1].z); a[7] = (short)f2bf(pa[slotA][1].w);
    bf16x8 bfr = *(const bf16x8*)(bufR ? rd1 : rd0);
    if (s + 3 < WVSTEPS) load_step(s + 3, slotA);
    acc = __builtin_amdgcn_mfma_f32_16x16x32_bf16(a, bfr, acc, 0, 0, 0);
    if (s + 1 < WVSTEPS) stage(slotN, bufN);
  };

  for (int ss = 0; ss < WVSTEPS; ss += 6) {   // 6 = lcm(3 slots, 2 bufs)
    body(ss + 0, 0, 0, 1, 1);
    body(ss + 1, 1, 1, 2, 0);
    body(ss + 2, 2, 0, 0, 1);
    body(ss + 3, 0, 1, 1, 0);
    body(ss + 4, 1, 0, 2, 1);
    body(ss + 5, 2, 1, 0, 0);
  }

  // ---- tail: 8-way reduce (fixed pairwise order), squash, store ----
  // C/D layout: col = m16 (=o), row = q*4 + r  ->  16x16 tile index (row*16+o)
#pragma unroll
  for (int r = 0; r < 4; ++r)
    redbuf[wv][(q * 4 + r) * 16 + m16] = acc[r];
  __syncthreads();

  if (tid < 256) {
    const float a01 = redbuf[0][tid] + redbuf[1][tid];
    const float a23 = redbuf[2][tid] + redbuf[3][tid];
    const float a45 = redbuf[4][tid] + redbuf[5][tid];
    const float a67 = redbuf[6][tid] + redbuf[7][tid];
    const float v   = ((a01 + a23) + (a45 + a67)) * (1.0f / (float)RNODES);

    float sq = v * v;                 // squash over the 16-lane o-group
    sq += __shfl_xor(sq, 1);
    sq += __shfl_xor(sq, 2);
    sq += __shfl_xor(sq, 4);
    sq += __shfl_xor(sq, 8);
    const float g = sqrtf(sq) / (1.0f + sq);

    out[n * 4096 + (b0 + (tid >> 4)) * 16 + (tid & 15)] = v * g;
  }
}

extern "C" void kernel_launch(void* const* d_in, const int* in_sizes, int n_in,
                              void* d_out, int out_size, void* d_ws, size_t ws_size,
                              hipStream_t stream) {
  const float* x = (const float*)d_in[0];   // [256,1152,8] fp32
  const float* W = (const float*)d_in[1];   // [10,1152,8,16] fp32
  float* out = (float*)d_out;               // 40960 fp32
  (void)d_ws; (void)ws_size;                // workspace unused (no split-K)

  caps_one<<<dim3(NBLK), dim3(512), 0, stream>>>(x, W, out);
}

// Round 3
// 73.690 us; speedup vs baseline: 1.9750x; 1.1135x over previous
//
#include <hip/hip_runtime.h>

#define RNODES 1152
#define KDIM 9216                 // 1152*8
#define COUT 16
#define NCAPS 10
#define WSTRIDE (KDIM*COUT)       // 147456 floats per capsule

#define LROW 40                   // 32 k + 8 pad (ushorts) -> 80B rows, 16B-aligned reads
#define WBUF (NCAPS*COUT*LROW)    // 6400 ushorts = 12.8 KB per buffer
#define STEPS 9                   // k-steps of 32 per block
#define SPLITS 32                 // 32 * 9 * 32 = 9216 = KDIM
#define NBLK 512                  // 16 M-tiles x 32 splits = 2 blocks/CU (R11 change)
#define MT 16                     // rows per block (R8 had 32)
#define PARTL (MT*COUT*NCAPS)     // 2560 floats per block partial (16 rows)
#define PARTL4 (PARTL/4)          // 640 float4

using bf16x8 = __attribute__((ext_vector_type(8))) short;
using f32x4  = __attribute__((ext_vector_type(4))) float;

// round-to-nearest (ties up): 2 VALU ops; unbiased to 2^-9 rel — same as R8.
__device__ __forceinline__ unsigned short f2bf(float f) {
  unsigned int u = __builtin_bit_cast(unsigned int, f);
  return (unsigned short)((u + 0x8000u) >> 16);
}

// R11: R8 gemm with the 32-row M-tile split into two 16-row tiles -> 512 blocks
// = 2 blocks/CU = 2 waves/SIMD. Evidence (R1 counters on the identical phase):
// MfmaUtil 0.35%, VALUBusy 1.4% -> ~98% stalled at 1 wave/SIMD; a co-resident
// second block hides the per-step barrier + vmcnt drains. Everything proven in
// R8 is kept byte-identical:
//  * bid = mt*32 + ks -> XCD = ks%8: all 16 mt-blocks sharing W-slice ks sit on
//    ONE XCD -> W re-reads are L2 hits (W HBM traffic stays ~5.9 MB).
//  * W staging decode slab-contiguous (u = j*256+tid): 1KB coalesced wave txns.
//  * LDS transpose layout + k-block rotation: writes 2-way aliasing (free),
//    reads 16B-aligned conflict-free ds_read_b128 (R8-verified).
//  * 3-deep register prefetch, one __syncthreads per step, 2-buffer parity.
// Capsule->wave split changes (only structural delta): 4 waves x 3 capsule
// slots (slots 10,11 dead: reads clamped to slot 0, stores skipped) instead of
// 2x5. Per-(16-row, capsule, ks) partial sums are bitwise-identical to R8.
__global__ __launch_bounds__(256, 2) void caps_gemm(const float* __restrict__ x,
                                                    const float* __restrict__ W,
                                                    float* __restrict__ ws) {
  __shared__ unsigned short wbuf[2][WBUF];   // ping-pong, 25.6 KB
  const int tid = threadIdx.x;
  const int bid = blockIdx.x;
  const int mt  = bid >> 5;         // 0..15 (16-row M-tile)
  const int ks  = bid & 31;         // 0..31 (K split)
  const int b0  = mt * MT;
  const int k0  = ks * (STEPS * 32);   // 288-element K chunk

  const int lane = tid & 63;
  const int wv   = tid >> 6;        // 0..3: capsule-triple slot
  const int q    = lane >> 4;       // k-quad
  const int m16  = lane & 15;

  // ---- slab-contiguous staging decode (5 units/thread covers 1280 float4) ----
  int u_n[5], u_kl[5], u_of[5];
#pragma unroll
  for (int j = 0; j < 5; ++j) {
    const int u  = j * 256 + tid;
    u_n[j]  = u >> 7;               // capsule slab 0..9
    const int rem = u & 127;
    u_kl[j] = rem >> 2;             // k within step, 0..31
    u_of[j] = (rem & 3) << 2;       // o-quad base 0,4,8,12
  }

  const float* xrow = x + (size_t)(b0 + m16) * KDIM + k0 + q * 8;

  float4 pw[3][5];
  float4 pa[3][2];

  auto load_step = [&](int s, int slot) {
#pragma unroll
    for (int j = 0; j < 5; ++j)
      pw[slot][j] = *(const float4*)(W + (size_t)u_n[j] * WSTRIDE +
                                     (size_t)(k0 + s * 32 + u_kl[j]) * COUT + u_of[j]);
    pa[slot][0] = *(const float4*)(xrow + s * 32);
    pa[slot][1] = *(const float4*)(xrow + s * 32 + 4);
  };

  load_step(0, 0);
  load_step(1, 1);
  load_step(2, 2);

  f32x4 acc[3];
#pragma unroll
  for (int i = 0; i < 3; ++i) acc[i] = (f32x4){0.f, 0.f, 0.f, 0.f};

  // per-lane rotated read quad (k-block) — capsule-independent (nt*16 ≡ 0 mod 4)
  const int qrot = (q + (m16 & 3) + (m16 >> 2)) & 3;
  // read offsets per capsule slot; dead slots (nt>=10) clamp to slot 0 so the
  // (discarded) MFMA reads stay inside the LDS allocation.
  int rdoff[3];
#pragma unroll
  for (int j = 0; j < 3; ++j) {
    const int nt  = wv * 3 + j;
    const int nt2 = (nt < NCAPS) ? nt : 0;
    rdoff[j] = (nt2 * COUT + m16) * LROW + (qrot << 3);
  }

#pragma unroll
  for (int s = 0; s < STEPS; ++s) {
    const int slot = s % 3;
    unsigned short* b = &wbuf[s & 1][0];
    // stage W step s: [col][k-rotated] bf16 transpose (byte-identical to R8)
#pragma unroll
    for (int j = 0; j < 5; ++j) {
      const int kl  = u_kl[j];
      const int klo = kl & 7, kblk = kl >> 3;
      const float* v = (const float*)&pw[slot][j];
#pragma unroll
      for (int r = 0; r < 4; ++r) {
        const int c   = u_n[j] * COUT + u_of[j] + r;
        const int pos = klo | (((kblk + (c & 3) + ((c >> 2) & 3)) & 3) << 3);
        b[c * LROW + pos] = f2bf(v[r]);
      }
    }
    __syncthreads();
    // write(s+2) to this parity happens after barrier(s+1); reads(s) drain
    // before barrier(s+1) -> classic 2-buffer safety, 1 barrier/step.

    bf16x8 a;
    a[0] = (short)f2bf(pa[slot][0].x); a[1] = (short)f2bf(pa[slot][0].y);
    a[2] = (short)f2bf(pa[slot][0].z); a[3] = (short)f2bf(pa[slot][0].w);
    a[4] = (short)f2bf(pa[slot][1].x); a[5] = (short)f2bf(pa[slot][1].y);
    a[6] = (short)f2bf(pa[slot][1].z); a[7] = (short)f2bf(pa[slot][1].w);

    if (s + 3 < STEPS) load_step(s + 3, slot);   // slot just freed

#pragma unroll
    for (int j = 0; j < 3; ++j) {
      bf16x8 bf = *(const bf16x8*)&b[rdoff[j]];
      acc[j] = __builtin_amdgcn_mfma_f32_16x16x32_bf16(a, bf, acc[j], 0, 0, 0);
    }
  }

  // ---- partial store: P[bid][n][row16][o] ----
  float* P = ws + (size_t)bid * PARTL;
  const int prow = q * 4;           // C/D: col=lane&15 (=o), row=q*4+reg
#pragma unroll
  for (int j = 0; j < 3; ++j) {
    const int nt = wv * 3 + j;
    if (nt < NCAPS) {
#pragma unroll
      for (int r = 0; r < 4; ++r)
        P[nt * (MT * COUT) + (prow + r) * COUT + m16] = acc[j][r];
    }
  }
}

// grid = 80 x 128: thread f owns output float4 f (f = n*1024 + b*4 + o4),
// sums 32 splits with fixed order (deterministic), squashes over 4-lane
// o-groups. Identical structure + summation order to R8 -> bitwise-identical
// output; only the partial indexing (16-row tiles) changed.
__global__ __launch_bounds__(128, 1) void caps_reduce(const float* __restrict__ ws,
                                                      float* __restrict__ out) {
  const int f  = blockIdx.x * 128 + threadIdx.x;   // 0..10239
  const int n  = f >> 10;
  const int b  = (f >> 2) & 255;
  const int o4 = f & 3;
  const int mt = b >> 4, row = b & 15;

  const float4* base = (const float4*)ws + (size_t)(mt * SPLITS) * PARTL4
                       + n * (MT * COUT / 4) + row * 4 + o4;
  float4 s0 = {0,0,0,0}, s1 = {0,0,0,0}, s2 = {0,0,0,0}, s3 = {0,0,0,0};
#pragma unroll
  for (int kk = 0; kk < SPLITS; kk += 4) {
    float4 a0 = base[(size_t)(kk + 0) * PARTL4];
    float4 a1 = base[(size_t)(kk + 1) * PARTL4];
    float4 a2 = base[(size_t)(kk + 2) * PARTL4];
    float4 a3 = base[(size_t)(kk + 3) * PARTL4];
    s0.x += a0.x; s0.y += a0.y; s0.z += a0.z; s0.w += a0.w;
    s1.x += a1.x; s1.y += a1.y; s1.z += a1.z; s1.w += a1.w;
    s2.x += a2.x; s2.y += a2.y; s2.z += a2.z; s2.w += a2.w;
    s3.x += a3.x; s3.y += a3.y; s3.z += a3.z; s3.w += a3.w;
  }
  const float inv = 1.0f / (float)RNODES;
  float4 s;
  s.x = ((s0.x + s1.x) + (s2.x + s3.x)) * inv;
  s.y = ((s0.y + s1.y) + (s2.y + s3.y)) * inv;
  s.z = ((s0.z + s1.z) + (s2.z + s3.z)) * inv;
  s.w = ((s0.w + s1.w) + (s2.w + s3.w)) * inv;

  float sq = s.x * s.x + s.y * s.y + s.z * s.z + s.w * s.w;
  sq += __shfl_xor(sq, 1);   // o-group of 16 = 4 adjacent lanes (o4 = f&3)
  sq += __shfl_xor(sq, 2);
  const float g = sqrtf(sq) / (1.0f + sq);
  s.x *= g; s.y *= g; s.z *= g; s.w *= g;

  ((float4*)out)[f] = s;     // out float4 index == f by construction
}

extern "C" void kernel_launch(void* const* d_in, const int* in_sizes, int n_in,
                              void* d_out, int out_size, void* d_ws, size_t ws_size,
                              hipStream_t stream) {
  const float* x = (const float*)d_in[0];   // [256,1152,8] fp32
  const float* W = (const float*)d_in[1];   // [10,1152,8,16] fp32
  float* ws  = (float*)d_ws;                // 512*2560 fp32 partials (5.2 MB)
  float* out = (float*)d_out;               // 40960 fp32

  caps_gemm<<<dim3(NBLK), dim3(256), 0, stream>>>(x, W, ws);
  caps_reduce<<<dim3(80), dim3(128), 0, stream>>>(ws, out);
}